// Round 1
// baseline (110.968 us; speedup 1.0000x reference)
//
#include <hip/hip_runtime.h>
#include <float.h>

// Chamfer distance, B=4, N=M=5000, D=3, fp32.
// cham = mean_i min_j |p_i - g_j|^2 + mean_j min_i |p_i - g_j|^2
// Both means are over B*N = 20000 rows -> sum all 40000 row-mins / 20000.

#define BB    4
#define NP    5000
#define CHUNK 500     // target points per j-chunk (LDS staged)
#define JC    10      // ceil(NP / CHUNK)
#define QPB   512     // query points per block = 256 threads * 2 rows
#define QBLKS 10      // ceil(NP / QPB)
#define NROWS (2 * BB * NP)   // 40000

__global__ __launch_bounds__(256) void dl_init_kernel(unsigned* __restrict__ rowmin) {
    int i = blockIdx.x * 256 + threadIdx.x;
    if (i < NROWS) rowmin[i] = 0x7F7FFFFFu;  // FLT_MAX bit pattern
}

__global__ __launch_bounds__(256) void dl_chamfer_kernel(
    const float* __restrict__ pred, const float* __restrict__ gt,
    unsigned* __restrict__ rowmin /* [2][BB*NP] */) {
    const int qblk  = blockIdx.x;   // 0..QBLKS-1
    const int chunk = blockIdx.y;   // 0..JC-1
    const int bz    = blockIdx.z;   // 0..2*BB-1
    const int b     = bz >> 1;
    const int dir   = bz & 1;       // 0: query=pred,target=gt; 1: swapped

    const float* qsrc = dir ? gt   : pred;
    const float* tsrc = dir ? pred : gt;

    // Stage target chunk into LDS as float4 (pad) — reads below are
    // wave-uniform j => bank broadcast, conflict-free.
    __shared__ float4 tg[CHUNK];
    const int jbase = chunk * CHUNK;
    const int jcnt  = (jbase + CHUNK <= NP) ? CHUNK : (NP - jbase);
    for (int j = threadIdx.x; j < jcnt; j += 256) {
        const float* p = tsrc + ((size_t)b * NP + jbase + j) * 3;
        tg[j] = make_float4(p[0], p[1], p[2], 0.0f);
    }
    __syncthreads();

    // Two query rows per thread (amortize LDS read, ILP in the fma chains).
    const int q0 = qblk * QPB + threadIdx.x;
    const int q1 = q0 + 256;
    const bool v0 = q0 < NP, v1 = q1 < NP;
    float x0 = 0.f, y0 = 0.f, z0 = 0.f, x1 = 0.f, y1 = 0.f, z1 = 0.f;
    if (v0) { const float* p = qsrc + ((size_t)b * NP + q0) * 3; x0 = p[0]; y0 = p[1]; z0 = p[2]; }
    if (v1) { const float* p = qsrc + ((size_t)b * NP + q1) * 3; x1 = p[0]; y1 = p[1]; z1 = p[2]; }

    float m0 = FLT_MAX, m1 = FLT_MAX;
    #pragma unroll 4
    for (int j = 0; j < jcnt; ++j) {
        const float4 g = tg[j];
        const float dx0 = x0 - g.x, dy0 = y0 - g.y, dz0 = z0 - g.z;
        const float d0 = dx0 * dx0 + dy0 * dy0 + dz0 * dz0;
        m0 = fminf(m0, d0);
        const float dx1 = x1 - g.x, dy1 = y1 - g.y, dz1 = z1 - g.z;
        const float d1 = dx1 * dx1 + dy1 * dy1 + dz1 * dz1;
        m1 = fminf(m1, d1);
    }

    // d2 >= 0 always (sum of squares) => float bits order-preserving as u32.
    unsigned* base = rowmin + (size_t)dir * (BB * NP) + (size_t)b * NP;
    if (v0) atomicMin(base + q0, __float_as_uint(m0));
    if (v1) atomicMin(base + q1, __float_as_uint(m1));
}

__global__ __launch_bounds__(1024) void dl_reduce_kernel(
    const unsigned* __restrict__ rowmin, float* __restrict__ out) {
    float s = 0.0f;
    for (int i = threadIdx.x; i < NROWS; i += 1024)
        s += __uint_as_float(rowmin[i]);
    // wave (64-lane) shuffle reduction
    for (int off = 32; off > 0; off >>= 1)
        s += __shfl_down(s, off, 64);
    __shared__ float wsum[16];
    const int wave = threadIdx.x >> 6;
    if ((threadIdx.x & 63) == 0) wsum[wave] = s;
    __syncthreads();
    if (threadIdx.x == 0) {
        float t = 0.0f;
        #pragma unroll
        for (int w = 0; w < 16; ++w) t += wsum[w];
        out[0] = t / (float)(BB * NP);  // both means share denominator 20000
    }
}

extern "C" void kernel_launch(void* const* d_in, const int* in_sizes, int n_in,
                              void* d_out, int out_size, void* d_ws, size_t ws_size,
                              hipStream_t stream) {
    const float* pred = (const float*)d_in[0];
    const float* gt   = (const float*)d_in[1];
    unsigned* rowmin  = (unsigned*)d_ws;   // 40000 u32 = 160 KB
    float* out        = (float*)d_out;

    dl_init_kernel<<<dim3((NROWS + 255) / 256), 256, 0, stream>>>(rowmin);
    dim3 grid(QBLKS, JC, 2 * BB);
    dl_chamfer_kernel<<<grid, 256, 0, stream>>>(pred, gt, rowmin);
    dl_reduce_kernel<<<1, 1024, 0, stream>>>(rowmin, out);
}